// Round 10
// baseline (138.375 us; speedup 1.0000x reference)
//
#include <hip/hip_runtime.h>
#include <stdint.h>
#include <math.h>

#define NB 4
#define NH 16
#define NS 1024
#define ND 64
#define QT 64            // q rows per block
#define KT 64            // k cols per tile
#define NKT (NS/KT)      // 16
#define LDH 72           // f16 row pad: 144B rows, 16B-aligned units
#define SCALE_LOG2E 14426.950408889634f   // 10000 * log2(e); softmax done base-2
#define P_THRESH 5.9604645e-8f            // 2^-24: below this, dropout mask provably irrelevant

// staged-block geometry (pre-split K/V image, swizzled, LDS-ready)
#define ARR_H (KT*LDH)           // 4608 f16 per array
#define STG_H (3*ARR_H)          // 13824 f16 = 27648 B per (bh,kt) block
#define STG_B (STG_H*2)          // 27648 bytes
#define NCHUNK (STG_B/1024)      // 27 wave-chunks of 1 KB
#define WS_NEED ((size_t)NB*NH*NKT*STG_B)   // 28,311,552 B

typedef _Float16 half8 __attribute__((ext_vector_type(8)));
typedef _Float16 half4 __attribute__((ext_vector_type(4)));
typedef float    f32x4 __attribute__((ext_vector_type(4)));

// XOR-swizzled half-index for a [rows][LDH] f16 array (T2; involution both sides).
__device__ __forceinline__ int swz(int row, int col){
  return row*LDH + ((((col>>3) ^ ((row>>2)&7)))<<3) + (col&7);
}

// ---------------- threefry2x32, key = (0, 42) ----------------
__device__ __forceinline__ void threefry2x32(uint32_t x0, uint32_t x1,
                                             uint32_t &o0, uint32_t &o1){
  const uint32_t ks0 = 0u, ks1 = 42u, ks2 = 0x1BD11BF0u; // 0x1BD11BDA ^ 0 ^ 42
  x0 += ks0; x1 += ks1;
#define TFR(r) { x0 += x1; x1 = __builtin_rotateleft32(x1,(r)); x1 ^= x0; }
  TFR(13) TFR(15) TFR(26) TFR(6)
  x0 += ks1; x1 += ks2 + 1u;
  TFR(17) TFR(29) TFR(16) TFR(24)
  x0 += ks2; x1 += ks0 + 2u;
  TFR(13) TFR(15) TFR(26) TFR(6)
  x0 += ks0; x1 += ks1 + 3u;
  TFR(17) TFR(29) TFR(16) TFR(24)
  x0 += ks1; x1 += ks2 + 4u;
  TFR(13) TFR(15) TFR(26) TFR(6)
  x0 += ks2; x1 += ks0 + 5u;
#undef TFR
  o0 = x0; o1 = x1;
}

// JAX partitionable threefry: bits(i) = o0^o1 of threefry(key, (0, i));
// keep iff (bits>>9) < 0x733333  (uniform < 0.9). Validated rounds 2..9.
__device__ __forceinline__ uint32_t keep_flat(uint32_t flat){
  uint32_t o0, o1;
  threefry2x32(0u, flat, o0, o1);
  return ((o0 ^ o1) >> 9) < 0x733333u ? 1u : 0u;
}

// async global->LDS, 16B per lane; LDS dest = uniform base + lane*16
__device__ __forceinline__ void gll16(const void* g, void* l){
  __builtin_amdgcn_global_load_lds(
      (const __attribute__((address_space(1))) void*)g,
      (__attribute__((address_space(3))) void*)l, 16, 0, 0);
}

// ---------------- pre-split kernel: K -> Khi/Klo f16, V -> V^T f16, swizzled image
__global__ __launch_bounds__(256) void presplit(
    const float* __restrict__ Kg, const float* __restrict__ Vg,
    _Float16* __restrict__ G)
{
  const int blk = blockIdx.x;          // bh*16 + kt
  const int bh = blk >> 4, kt = blk & 15;
  const float* Ks = Kg + ((size_t)bh*NS + kt*KT)*ND;
  const float* Vs = Vg + ((size_t)bh*NS + kt*KT)*ND;
  _Float16* SB = G + (size_t)blk * STG_H;

  const int t  = threadIdx.x;
  const int kc = t >> 2;               // row 0..63
  const int c0 = (t & 3) * 16;         // 16-col slice

  __shared__ float vt[64][68];

  // ---- K: read 16 cols, hi/lo split, write 2 swizzled 16B units each
  float xk[16];
  *(float4*)&xk[0]  = *(const float4*)(Ks + kc*ND + c0);
  *(float4*)&xk[4]  = *(const float4*)(Ks + kc*ND + c0 + 4);
  *(float4*)&xk[8]  = *(const float4*)(Ks + kc*ND + c0 + 8);
  *(float4*)&xk[12] = *(const float4*)(Ks + kc*ND + c0 + 12);
  half8 h0, h1, l0, l1;
  #pragma unroll
  for (int j = 0; j < 8; ++j) {
    _Float16 h = (_Float16)xk[j];
    h0[j] = h; l0[j] = (_Float16)(xk[j] - (float)h);
    _Float16 g = (_Float16)xk[8+j];
    h1[j] = g; l1[j] = (_Float16)(xk[8+j] - (float)g);
  }
  {
    const int xr = (kc>>2)&7;
    const int u0 = ((c0>>3) ^ xr) << 3;
    const int u1 = (((c0>>3)+1) ^ xr) << 3;
    *(half8*)&SB[0*ARR_H + kc*LDH + u0] = h0;
    *(half8*)&SB[0*ARR_H + kc*LDH + u1] = h1;
    *(half8*)&SB[1*ARR_H + kc*LDH + u0] = l0;
    *(half8*)&SB[1*ARR_H + kc*LDH + u1] = l1;
  }

  // ---- V: stage f32 tile to LDS, then transposed f16 write
  {
    float4 v0 = *(const float4*)(Vs + kc*ND + c0);
    float4 v1 = *(const float4*)(Vs + kc*ND + c0 + 4);
    float4 v2 = *(const float4*)(Vs + kc*ND + c0 + 8);
    float4 v3 = *(const float4*)(Vs + kc*ND + c0 + 12);
    *(float4*)&vt[kc][c0]      = v0;
    *(float4*)&vt[kc][c0 + 4]  = v1;
    *(float4*)&vt[kc][c0 + 8]  = v2;
    *(float4*)&vt[kc][c0 + 12] = v3;
  }
  __syncthreads();
  {
    const int d = t >> 2;              // output row (d), cols = kc range c0..c0+15
    half8 g0, g1;
    #pragma unroll
    for (int j = 0; j < 8; ++j) {
      g0[j] = (_Float16)vt[c0 + j][d];
      g1[j] = (_Float16)vt[c0 + 8 + j][d];
    }
    const int xr = (d>>2)&7;
    *(half8*)&SB[2*ARR_H + d*LDH + (((c0>>3) ^ xr) << 3)]     = g0;
    *(half8*)&SB[2*ARR_H + d*LDH + ((((c0>>3)+1) ^ xr) << 3)] = g1;
  }
}

// ---------------- main kernel: DMA-staged MFMA flash attention, fused lazy dropout
__global__ __launch_bounds__(256, 2) void attn_gll(
    const float* __restrict__ Qg, const _Float16* __restrict__ G,
    float* __restrict__ Og)
{
  __shared__ _Float16 buf[2][STG_H];   // Khi | Klo | Vt images (swizzled)
  __shared__ _Float16 Pl[4*16*LDH];    // per-wave P [q][kc] swizzled

  const int tid  = threadIdx.x;
  const int wid  = tid >> 6;
  const int lane = tid & 63;
  const int lhi  = lane >> 4;
  const int llo  = lane & 15;

  // bijective XCD swizzle: 1024 blocks, 8 XCDs, 128 contiguous work items each
  const int swzb = (blockIdx.x & 7) * 128 + (blockIdx.x >> 3);
  const int bh  = swzb >> 4;
  const int qt  = swzb & 15;

  // ---- Q A-fragments (registers for whole kernel), hi/lo fp16 split
  half8 qhi[2], qlo[2];
  {
    const float* qsrc = Qg + ((size_t)bh*NS + qt*QT + wid*16 + llo)*ND;
    #pragma unroll
    for (int ks = 0; ks < 2; ++ks) {
      const float* p = qsrc + ks*32 + lhi*8;
      float4 a = *(const float4*)p;
      float4 b = *(const float4*)(p + 4);
      float v[8] = {a.x,a.y,a.z,a.w,b.x,b.y,b.z,b.w};
      #pragma unroll
      for (int j = 0; j < 8; ++j) {
        _Float16 h = (_Float16)v[j];
        qhi[ks][j] = h;
        qlo[ks][j] = (_Float16)(v[j] - (float)h);
      }
    }
  }

  const char* gbase = (const char*)(G + (size_t)bh*NKT*STG_H);

  // issue 27 x 1KB DMA chunks for tile kt into buf[kt&1]
  auto issue = [&](int kt){
    const char* src = gbase + (size_t)kt*STG_B;
    char* dst = (char*)&buf[kt&1][0];
    for (int c = wid; c < NCHUNK; c += 4)
      gll16(src + c*1024 + lane*16, dst + c*1024);
  };

  issue(0);

  f32x4 Oacc[4];
  #pragma unroll
  for (int nt=0;nt<4;++nt){ Oacc[nt][0]=0.f;Oacc[nt][1]=0.f;Oacc[nt][2]=0.f;Oacc[nt][3]=0.f; }
  float m_run[4] = {-INFINITY,-INFINITY,-INFINITY,-INFINITY};   // scaled-log2 units
  float l_run[4] = {0.f,0.f,0.f,0.f};
  const uint32_t rowflat_base = (uint32_t)(bh*NS + qt*QT + wid*16);

  for (int kt = 0; kt < NKT; ++kt) {
    // Single barrier per tile: implicit vmcnt/lgkm drain => tile kt DMA landed,
    // and all waves finished reading buf[(kt-1)&1] (overwritten by kt+1's DMA).
    __syncthreads();
    if (kt + 1 < NKT) issue(kt + 1);

    const _Float16* Khi = &buf[kt&1][0];
    const _Float16* Klo = &buf[kt&1][ARR_H];
    const _Float16* Vt  = &buf[kt&1][2*ARR_H];

    // ---- QK^T via 3-product fp16 split; acc fp32
    f32x4 S[4];
    #pragma unroll
    for (int nt=0;nt<4;++nt){ S[nt][0]=0.f;S[nt][1]=0.f;S[nt][2]=0.f;S[nt][3]=0.f; }
    #pragma unroll
    for (int ks = 0; ks < 2; ++ks) {
      #pragma unroll
      for (int nt = 0; nt < 4; ++nt) {
        const int ki = swz(nt*16 + llo, ks*32 + lhi*8);
        half8 bh_ = *(const half8*)&Khi[ki];
        half8 bl_ = *(const half8*)&Klo[ki];
        S[nt] = __builtin_amdgcn_mfma_f32_16x16x32_f16(qhi[ks], bh_, S[nt], 0, 0, 0);
        S[nt] = __builtin_amdgcn_mfma_f32_16x16x32_f16(qlo[ks], bh_, S[nt], 0, 0, 0);
        S[nt] = __builtin_amdgcn_mfma_f32_16x16x32_f16(qhi[ks], bl_, S[nt], 0, 0, 0);
      }
    }

    // ---- online softmax in base-2 (C-layout: row=4*lhi+reg, col=nt*16+llo)
    float alpha[4];
    #pragma unroll
    for (int reg = 0; reg < 4; ++reg) {
      #pragma unroll
      for (int nt = 0; nt < 4; ++nt) S[nt][reg] *= SCALE_LOG2E;
      float tm = fmaxf(fmaxf(S[0][reg], S[1][reg]), fmaxf(S[2][reg], S[3][reg]));
      #pragma unroll
      for (int off = 1; off < 16; off <<= 1) tm = fmaxf(tm, __shfl_xor(tm, off));
      float mnew = fmaxf(m_run[reg], tm);
      float al   = exp2f(m_run[reg] - mnew);
      m_run[reg] = mnew;
      float ps = 0.f;
      #pragma unroll
      for (int nt = 0; nt < 4; ++nt) {
        float p = exp2f(S[nt][reg] - mnew);
        S[nt][reg] = p;
        ps += p;
      }
      #pragma unroll
      for (int off = 1; off < 16; off <<= 1) ps += __shfl_xor(ps, off);
      l_run[reg] = l_run[reg]*al + ps;
      alpha[reg] = al;
    }
    #pragma unroll
    for (int nt = 0; nt < 4; ++nt)
      #pragma unroll
      for (int reg = 0; reg < 4; ++reg) Oacc[nt][reg] *= alpha[reg];

    // ---- pass 1: branch-free P staging + need mask (ends S live range)
    _Float16* Pw = Pl + wid*16*LDH;
    uint32_t need16 = 0u;
    #pragma unroll
    for (int reg = 0; reg < 4; ++reg) {
      const int ql = lhi*4 + reg;
      #pragma unroll
      for (int nt = 0; nt < 4; ++nt) {
        float p = S[nt][reg];
        if (p > P_THRESH) need16 |= 1u << (reg*4 + nt);
        Pw[swz(ql, nt*16 + llo)] = (_Float16)p;
      }
    }
    // ---- pass 2: lazy exact-RNG zeroing (writes only constants; phi-free)
    #pragma unroll
    for (int reg = 0; reg < 4; ++reg) {
      const int ql = lhi*4 + reg;
      const uint32_t fb = (rowflat_base + ql)*NS + (uint32_t)(kt*KT + llo);
      #pragma unroll
      for (int nt = 0; nt < 4; ++nt) {
        if (__any((int)(need16 & (1u << (reg*4 + nt))))) {
          if (!keep_flat(fb + nt*16))
            Pw[swz(ql, nt*16 + llo)] = (_Float16)0.f;
        }
      }
    }

    // ---- PV: O += P(16x64) * V(64x64), fp16 MFMA (same k-map for A and B)
    #pragma unroll
    for (int ks = 0; ks < 2; ++ks) {
      half8 pa = *(const half8*)&Pw[swz(llo, ks*32 + lhi*8)];
      #pragma unroll
      for (int nt = 0; nt < 4; ++nt) {
        half8 vb = *(const half8*)&Vt[swz(nt*16 + llo, ks*32 + lhi*8)];
        Oacc[nt] = __builtin_amdgcn_mfma_f32_16x16x32_f16(pa, vb, Oacc[nt], 0, 0, 0);
      }
    }
  }

  // ---- epilogue: / l_run and / (1-p)
  float sc[4];
  #pragma unroll
  for (int reg = 0; reg < 4; ++reg) sc[reg] = (1.0f/0.9f) / l_run[reg];
  #pragma unroll
  for (int reg = 0; reg < 4; ++reg) {
    const size_t rowoff = ((size_t)bh*NS + qt*QT + wid*16 + lhi*4 + reg)*ND;
    #pragma unroll
    for (int nt = 0; nt < 4; ++nt)
      Og[rowoff + nt*16 + llo] = Oacc[nt][reg] * sc[reg];
  }
}

// ---------------- fallback (R9 kernel, unchanged): used if ws too small ----------------
__global__ __launch_bounds__(256, 3) void attn_fb(
    const float* __restrict__ Qg, const float* __restrict__ Kg,
    const float* __restrict__ Vg, float* __restrict__ Og)
{
  __shared__ _Float16 Khi[KT*LDH];
  __shared__ _Float16 Klo[KT*LDH];
  __shared__ _Float16 Vt [ND*LDH];
  __shared__ _Float16 Pl [4*16*LDH];

  const int tid  = threadIdx.x;
  const int wid  = tid >> 6;
  const int lane = tid & 63;
  const int lhi  = lane >> 4;
  const int llo  = lane & 15;
  const int swzb = (blockIdx.x & 7) * 128 + (blockIdx.x >> 3);
  const int bh  = swzb >> 4;
  const int qt  = swzb & 15;

  half8 qhi[2], qlo[2];
  {
    const float* qsrc = Qg + ((size_t)bh*NS + qt*QT + wid*16 + llo)*ND;
    #pragma unroll
    for (int ks = 0; ks < 2; ++ks) {
      const float* p = qsrc + ks*32 + lhi*8;
      float4 a = *(const float4*)p;
      float4 b = *(const float4*)(p + 4);
      float v[8] = {a.x,a.y,a.z,a.w,b.x,b.y,b.z,b.w};
      #pragma unroll
      for (int j = 0; j < 8; ++j) {
        _Float16 h = (_Float16)v[j];
        qhi[ks][j] = h;
        qlo[ks][j] = (_Float16)(v[j] - (float)h);
      }
    }
  }

  const float* srcK = Kg + (size_t)bh*NS*ND;
  const float* srcV = Vg + (size_t)bh*NS*ND;
  const int frow = tid >> 4;
  const int fcol = (tid & 15) * 4;

  float4 pk[4], pv[4];
  #pragma unroll
  for (int r = 0; r < 4; ++r) {
    const size_t off = (size_t)(frow + 16*r)*ND + fcol;
    pk[r] = *(const float4*)(srcK + off);
    pv[r] = *(const float4*)(srcV + off);
  }

  f32x4 Oacc[4];
  #pragma unroll
  for (int nt=0;nt<4;++nt){ Oacc[nt][0]=0.f;Oacc[nt][1]=0.f;Oacc[nt][2]=0.f;Oacc[nt][3]=0.f; }
  float m_run[4] = {-INFINITY,-INFINITY,-INFINITY,-INFINITY};
  float l_run[4] = {0.f,0.f,0.f,0.f};
  const uint32_t rowflat_base = (uint32_t)(bh*NS + qt*QT + wid*16);

  for (int kt = 0; kt < NKT; ++kt) {
    __syncthreads();
    #pragma unroll
    for (int r = 0; r < 4; ++r) {
      const int row = frow + 16*r;
      float vals[4] = {pk[r].x, pk[r].y, pk[r].z, pk[r].w};
      half4 h4, l4;
      #pragma unroll
      for (int j = 0; j < 4; ++j) {
        _Float16 h = (_Float16)vals[j];
        h4[j] = h;
        l4[j] = (_Float16)(vals[j] - (float)h);
      }
      const int ki = swz(row, fcol);
      *(half4*)&Khi[ki] = h4;
      *(half4*)&Klo[ki] = l4;
      float vv[4] = {pv[r].x, pv[r].y, pv[r].z, pv[r].w};
      #pragma unroll
      for (int j = 0; j < 4; ++j)
        Vt[swz(fcol+j, row)] = (_Float16)vv[j];
    }
    __syncthreads();
    if (kt + 1 < NKT) {
      #pragma unroll
      for (int r = 0; r < 4; ++r) {
        const size_t off = (size_t)((kt+1)*KT + frow + 16*r)*ND + fcol;
        pk[r] = *(const float4*)(srcK + off);
        pv[r] = *(const float4*)(srcV + off);
      }
    }

    f32x4 S[4];
    #pragma unroll
    for (int nt=0;nt<4;++nt){ S[nt][0]=0.f;S[nt][1]=0.f;S[nt][2]=0.f;S[nt][3]=0.f; }
    #pragma unroll
    for (int ks = 0; ks < 2; ++ks) {
      #pragma unroll
      for (int nt = 0; nt < 4; ++nt) {
        const int ki = swz(nt*16 + llo, ks*32 + lhi*8);
        half8 bh_ = *(const half8*)&Khi[ki];
        half8 bl_ = *(const half8*)&Klo[ki];
        S[nt] = __builtin_amdgcn_mfma_f32_16x16x32_f16(qhi[ks], bh_, S[nt], 0, 0, 0);
        S[nt] = __builtin_amdgcn_mfma_f32_16x16x32_f16(qlo[ks], bh_, S[nt], 0, 0, 0);
        S[nt] = __builtin_amdgcn_mfma_f32_16x16x32_f16(qhi[ks], bl_, S[nt], 0, 0, 0);
      }
    }

    float alpha[4];
    #pragma unroll
    for (int reg = 0; reg < 4; ++reg) {
      #pragma unroll
      for (int nt = 0; nt < 4; ++nt) S[nt][reg] *= SCALE_LOG2E;
      float tm = fmaxf(fmaxf(S[0][reg], S[1][reg]), fmaxf(S[2][reg], S[3][reg]));
      #pragma unroll
      for (int off = 1; off < 16; off <<= 1) tm = fmaxf(tm, __shfl_xor(tm, off));
      float mnew = fmaxf(m_run[reg], tm);
      float al   = exp2f(m_run[reg] - mnew);
      m_run[reg] = mnew;
      float ps = 0.f;
      #pragma unroll
      for (int nt = 0; nt < 4; ++nt) {
        float p = exp2f(S[nt][reg] - mnew);
        S[nt][reg] = p;
        ps += p;
      }
      #pragma unroll
      for (int off = 1; off < 16; off <<= 1) ps += __shfl_xor(ps, off);
      l_run[reg] = l_run[reg]*al + ps;
      alpha[reg] = al;
    }
    #pragma unroll
    for (int nt = 0; nt < 4; ++nt)
      #pragma unroll
      for (int reg = 0; reg < 4; ++reg) Oacc[nt][reg] *= alpha[reg];

    _Float16* Pw = Pl + wid*16*LDH;
    uint32_t need16 = 0u;
    #pragma unroll
    for (int reg = 0; reg < 4; ++reg) {
      const int ql = lhi*4 + reg;
      #pragma unroll
      for (int nt = 0; nt < 4; ++nt) {
        float p = S[nt][reg];
        if (p > P_THRESH) need16 |= 1u << (reg*4 + nt);
        Pw[swz(ql, nt*16 + llo)] = (_Float16)p;
      }
    }
    #pragma unroll
    for (int reg = 0; reg < 4; ++reg) {
      const int ql = lhi*4 + reg;
      const uint32_t fb = (rowflat_base + ql)*NS + (uint32_t)(kt*KT + llo);
      #pragma unroll
      for (int nt = 0; nt < 4; ++nt) {
        if (__any((int)(need16 & (1u << (reg*4 + nt))))) {
          if (!keep_flat(fb + nt*16))
            Pw[swz(ql, nt*16 + llo)] = (_Float16)0.f;
        }
      }
    }

    #pragma unroll
    for (int ks = 0; ks < 2; ++ks) {
      half8 pa = *(const half8*)&Pw[swz(llo, ks*32 + lhi*8)];
      #pragma unroll
      for (int nt = 0; nt < 4; ++nt) {
        half8 vb = *(const half8*)&Vt[swz(nt*16 + llo, ks*32 + lhi*8)];
        Oacc[nt] = __builtin_amdgcn_mfma_f32_16x16x32_f16(pa, vb, Oacc[nt], 0, 0, 0);
      }
    }
  }

  float sc[4];
  #pragma unroll
  for (int reg = 0; reg < 4; ++reg) sc[reg] = (1.0f/0.9f) / l_run[reg];
  #pragma unroll
  for (int reg = 0; reg < 4; ++reg) {
    const size_t rowoff = ((size_t)bh*NS + qt*QT + wid*16 + lhi*4 + reg)*ND;
    #pragma unroll
    for (int nt = 0; nt < 4; ++nt)
      Og[rowoff + nt*16 + llo] = Oacc[nt][reg] * sc[reg];
  }
}

extern "C" void kernel_launch(void* const* d_in, const int* in_sizes, int n_in,
                              void* d_out, int out_size, void* d_ws, size_t ws_size,
                              hipStream_t stream) {
  const float* x1  = (const float*)d_in[0];   // Q
  const float* kw  = (const float*)d_in[1];   // K
  const float* val = (const float*)d_in[2];   // V
  float* out = (float*)d_out;

  if (ws_size >= WS_NEED) {
    _Float16* G = (_Float16*)d_ws;
    presplit<<<dim3(NB*NH*NKT), dim3(256), 0, stream>>>(kw, val, G);
    attn_gll<<<dim3(NB*NH*(NS/QT)), dim3(256), 0, stream>>>(x1, G, out);
  } else {
    attn_fb<<<dim3(NB*NH*(NS/QT)), dim3(256), 0, stream>>>(x1, kw, val, out);
  }
}

// Round 11
// 104.469 us; speedup vs baseline: 1.3246x; 1.3246x over previous
//
#include <hip/hip_runtime.h>
#include <stdint.h>
#include <math.h>

#define NB 4
#define NH 16
#define NS 1024
#define ND 64
#define QT 64            // q rows per block
#define KT 64            // k cols per tile
#define NKT (NS/KT)      // 16
#define LDH 72           // f16 row pad: 144B rows, 16B-aligned units
#define SCALE_LOG2E 14426.950408889634f   // 10000 * log2(e); softmax done base-2
#define P_THRESH 5.9604645e-8f            // 2^-24: below this, dropout mask provably irrelevant

typedef _Float16 half8  __attribute__((ext_vector_type(8)));
typedef _Float16 half4  __attribute__((ext_vector_type(4)));
typedef _Float16 half2v __attribute__((ext_vector_type(2)));
typedef float    f32x4  __attribute__((ext_vector_type(4)));
typedef uint32_t uint4v __attribute__((ext_vector_type(4)));

// XOR-swizzled half-index for a [rows][LDH] f16 LDS array (T2; involution both sides).
__device__ __forceinline__ int swz(int row, int col){
  return row*LDH + ((((col>>3) ^ ((row>>2)&7)))<<3) + (col&7);
}

// ---------------- threefry2x32, key = (0, 42) ----------------
__device__ __forceinline__ void threefry2x32(uint32_t x0, uint32_t x1,
                                             uint32_t &o0, uint32_t &o1){
  const uint32_t ks0 = 0u, ks1 = 42u, ks2 = 0x1BD11BF0u; // 0x1BD11BDA ^ 0 ^ 42
  x0 += ks0; x1 += ks1;
#define TFR(r) { x0 += x1; x1 = __builtin_rotateleft32(x1,(r)); x1 ^= x0; }
  TFR(13) TFR(15) TFR(26) TFR(6)
  x0 += ks1; x1 += ks2 + 1u;
  TFR(17) TFR(29) TFR(16) TFR(24)
  x0 += ks2; x1 += ks0 + 2u;
  TFR(13) TFR(15) TFR(26) TFR(6)
  x0 += ks0; x1 += ks1 + 3u;
  TFR(17) TFR(29) TFR(16) TFR(24)
  x0 += ks1; x1 += ks2 + 4u;
  TFR(13) TFR(15) TFR(26) TFR(6)
  x0 += ks2; x1 += ks0 + 5u;
#undef TFR
  o0 = x0; o1 = x1;
}

// JAX partitionable threefry: bits(i) = o0^o1 of threefry(key, (0, i));
// keep iff (bits>>9) < 0x733333  (uniform < 0.9). Validated rounds 2..10.
__device__ __forceinline__ uint32_t keep_flat(uint32_t flat){
  uint32_t o0, o1;
  threefry2x32(0u, flat, o0, o1);
  return ((o0 ^ o1) >> 9) < 0x733333u ? 1u : 0u;
}

// MFMA flash attention, swapped-operand PV (P in registers, no P LDS array).
// S^T = mfma(K, Q): verified C/D layout gives lane (lhi,llo) the full q-row
// slice q=llo, k = nt*16 + 4*lhi + reg. Softmax is per-lane + 2 shfl_xor.
// PV: O^T = mfma(V, P^T); P^T B-frags built in-register via shfl+cndmask —
// permutation-safe (A and B constructed with the same assumed k-map; all k
// indexing for dropout uses only the verified C/D layout).
__global__ __launch_bounds__(256, 3) void attn_swp(
    const float* __restrict__ Qg, const float* __restrict__ Kg,
    const float* __restrict__ Vg, float* __restrict__ Og)
{
  __shared__ _Float16 Khi[KT*LDH];        // K hi parts, [kc][d] swizzled
  __shared__ _Float16 Klo[KT*LDH];        // K lo parts
  __shared__ _Float16 Vt [ND*LDH];        // V transposed [d][kc] swizzled

  const int tid  = threadIdx.x;
  const int wid  = tid >> 6;
  const int lane = tid & 63;
  const int lhi  = lane >> 4;     // 0..3
  const int llo  = lane & 15;

  // bijective XCD swizzle: 1024 blocks, 8 XCDs, 128 contiguous work items each
  const int swzb = (blockIdx.x & 7) * 128 + (blockIdx.x >> 3);
  const int bh  = swzb >> 4;
  const int qt  = swzb & 15;

  // shuffle source lanes for P^T B-frag build (w<2 -> sl0, w>=2 -> sl1)
  const int sl0 = ((lane & 16) << 1) + llo;   // (lhi&1)*32 + llo
  const int sl1 = sl0 + 16;

  // ---- Q B-fragments (registers for whole kernel), hi/lo fp16 split
  half8 qhi[2], qlo[2];
  {
    const float* qsrc = Qg + ((size_t)bh*NS + qt*QT + wid*16 + llo)*ND;
    #pragma unroll
    for (int ks = 0; ks < 2; ++ks) {
      const float* p = qsrc + ks*32 + lhi*8;
      float4 a = *(const float4*)p;
      float4 b = *(const float4*)(p + 4);
      float v[8] = {a.x,a.y,a.z,a.w,b.x,b.y,b.z,b.w};
      #pragma unroll
      for (int j = 0; j < 8; ++j) {
        _Float16 h = (_Float16)v[j];
        qhi[ks][j] = h;
        qlo[ks][j] = (_Float16)(v[j] - (float)h);
      }
    }
  }

  const float* srcK = Kg + (size_t)bh*NS*ND;
  const float* srcV = Vg + (size_t)bh*NS*ND;
  const int frow = tid >> 4;          // 0..15 (global-load row within 256-thread sweep)
  const int fcol = (tid & 15) * 4;    // d offset

  float4 pk[4], pv[4];
  #pragma unroll
  for (int r = 0; r < 4; ++r) {       // prefetch tile 0
    const size_t off = (size_t)(frow + 16*r)*ND + fcol;
    pk[r] = *(const float4*)(srcK + off);
    pv[r] = *(const float4*)(srcV + off);
  }

  f32x4 Oacc[4];                      // O^T: lane holds [d=nt*16+4lhi+reg][q=llo]
  #pragma unroll
  for (int nt=0;nt<4;++nt){ Oacc[nt][0]=0.f;Oacc[nt][1]=0.f;Oacc[nt][2]=0.f;Oacc[nt][3]=0.f; }
  float m_run = -INFINITY;            // scalar per lane (q=llo), scaled-log2 units
  float l_run = 0.f;
  const uint32_t qrow_flat = (uint32_t)(bh*NS + qt*QT + wid*16 + llo);

  for (int kt = 0; kt < NKT; ++kt) {
    __syncthreads();   // A: all waves' prior-tile LDS reads complete
    // ---- LDS write phase (consumes pk/pv; compiler inserts vmcnt wait)
    #pragma unroll
    for (int r = 0; r < 4; ++r) {
      const int row = frow + 16*r;    // kc 0..63
      float vals[4] = {pk[r].x, pk[r].y, pk[r].z, pk[r].w};
      half4 h4, l4;
      #pragma unroll
      for (int j = 0; j < 4; ++j) {
        _Float16 h = (_Float16)vals[j];
        h4[j] = h;
        l4[j] = (_Float16)(vals[j] - (float)h);
      }
      const int ki = swz(row, fcol);  // fcol&7 ∈ {0,4}: 8B stays in one 16B unit
      *(half4*)&Khi[ki] = h4;
      *(half4*)&Klo[ki] = l4;
      float vv[4] = {pv[r].x, pv[r].y, pv[r].z, pv[r].w};
      #pragma unroll
      for (int j = 0; j < 4; ++j)
        Vt[swz(fcol+j, row)] = (_Float16)vv[j];   // transposed scalar, swizzled
    }
    __syncthreads();   // B: tiles ready
    // ---- issue next tile's global loads (latency hidden under compute)
    if (kt + 1 < NKT) {
      #pragma unroll
      for (int r = 0; r < 4; ++r) {
        const size_t off = (size_t)((kt+1)*KT + frow + 16*r)*ND + fcol;
        pk[r] = *(const float4*)(srcK + off);
        pv[r] = *(const float4*)(srcV + off);
      }
    }

    // ---- swapped QK^T: S^T[k][q] via 3-product fp16 split; acc fp32
    f32x4 St[4];
    #pragma unroll
    for (int nt=0;nt<4;++nt){ St[nt][0]=0.f;St[nt][1]=0.f;St[nt][2]=0.f;St[nt][3]=0.f; }
    #pragma unroll
    for (int ks = 0; ks < 2; ++ks) {
      #pragma unroll
      for (int nt = 0; nt < 4; ++nt) {
        const int ki = swz(nt*16 + llo, ks*32 + lhi*8);
        half8 kh = *(const half8*)&Khi[ki];
        half8 kl = *(const half8*)&Klo[ki];
        St[nt] = __builtin_amdgcn_mfma_f32_16x16x32_f16(kh, qhi[ks], St[nt], 0, 0, 0);
        St[nt] = __builtin_amdgcn_mfma_f32_16x16x32_f16(kh, qlo[ks], St[nt], 0, 0, 0);
        St[nt] = __builtin_amdgcn_mfma_f32_16x16x32_f16(kl, qhi[ks], St[nt], 0, 0, 0);
      }
    }

    // ---- per-lane online softmax in base-2 (lane owns row q=llo, 16 k-values)
    #pragma unroll
    for (int nt = 0; nt < 4; ++nt)
      #pragma unroll
      for (int r = 0; r < 4; ++r) St[nt][r] *= SCALE_LOG2E;
    float tm = -INFINITY;
    #pragma unroll
    for (int nt = 0; nt < 4; ++nt) {
      float a = fmaxf(fmaxf(St[nt][0], St[nt][1]), fmaxf(St[nt][2], St[nt][3]));
      tm = fmaxf(tm, a);
    }
    tm = fmaxf(tm, __shfl_xor(tm, 16));
    tm = fmaxf(tm, __shfl_xor(tm, 32));
    const float mnew = fmaxf(m_run, tm);
    const float al   = exp2f(m_run - mnew);
    m_run = mnew;
    float ps = 0.f;
    #pragma unroll
    for (int nt = 0; nt < 4; ++nt) {
      #pragma unroll
      for (int r = 0; r < 4; ++r) {
        float p = exp2f(St[nt][r] - mnew);
        St[nt][r] = p;
        ps += p;
      }
    }
    ps += __shfl_xor(ps, 16);
    ps += __shfl_xor(ps, 32);
    l_run = l_run*al + ps;
    #pragma unroll
    for (int nt = 0; nt < 4; ++nt) {
      Oacc[nt][0]*=al; Oacc[nt][1]*=al; Oacc[nt][2]*=al; Oacc[nt][3]*=al;
    }

    // ---- need mask (element i = nt*4+reg -> k = nt*16 + 4*lhi + reg)
    uint32_t nm = 0u;
    #pragma unroll
    for (int i = 0; i < 16; ++i)
      if (St[i>>2][i&3] > P_THRESH) nm |= 1u << i;

    // ---- cvt P to packed fp16 (8 u32); ends St's f32 live range
    uint32_t p16[8];
    #pragma unroll
    for (int w = 0; w < 8; ++w) {
      half2v h;
      h[0] = (_Float16)St[w>>1][(2*w)&3];
      h[1] = (_Float16)St[w>>1][(2*w+1)&3];
      p16[w] = __builtin_bit_cast(uint32_t, h);
    }

    // ---- lazy exact-RNG: branches only update the 16-bit keep mask
    uint32_t km = 0xFFFFu;
    const uint32_t fb = qrow_flat*NS + (uint32_t)(kt*KT + 4*lhi);
    #pragma unroll
    for (int i = 0; i < 16; ++i) {
      if (__any((int)(nm & (1u << i)))) {
        if (!keep_flat(fb + (uint32_t)((i>>2)*16 + (i&3))))
          km &= ~(1u << i);
      }
    }
    #pragma unroll
    for (int w = 0; w < 8; ++w) {
      uint32_t msk = (((km >> (2*w)) & 1u) ? 0x0000FFFFu : 0u)
                   | (((km >> (2*w+1)) & 1u) ? 0xFFFF0000u : 0u);
      p16[w] &= msk;
    }

    // ---- PV: O^T += V * P^T  (A = V frags from Vt, B = P^T built via shfl)
    #pragma unroll
    for (int ks = 0; ks < 2; ++ks) {
      uint4v bw;
      #pragma unroll
      for (int w = 0; w < 4; ++w) {
        const int src = (w < 2) ? sl0 : sl1;
        uint32_t a = (uint32_t)__shfl((int)p16[4*ks + (w&1)],     src);
        uint32_t b = (uint32_t)__shfl((int)p16[4*ks + 2 + (w&1)], src);
        bw[w] = (lane & 32) ? b : a;
      }
      half8 pb = __builtin_bit_cast(half8, bw);
      #pragma unroll
      for (int nt = 0; nt < 4; ++nt) {
        half8 vb = *(const half8*)&Vt[swz(nt*16 + llo, ks*32 + lhi*8)];
        Oacc[nt] = __builtin_amdgcn_mfma_f32_16x16x32_f16(vb, pb, Oacc[nt], 0, 0, 0);
      }
    }
  }

  // ---- epilogue: O^T lane rows are contiguous d -> float4 stores
  const float sc = (1.0f/0.9f) / l_run;
  const size_t rowbase = ((size_t)bh*NS + qt*QT + wid*16 + llo)*ND;
  #pragma unroll
  for (int nt = 0; nt < 4; ++nt) {
    float4 o;
    o.x = Oacc[nt][0]*sc; o.y = Oacc[nt][1]*sc;
    o.z = Oacc[nt][2]*sc; o.w = Oacc[nt][3]*sc;
    *(float4*)(Og + rowbase + nt*16 + 4*lhi) = o;
  }
}

extern "C" void kernel_launch(void* const* d_in, const int* in_sizes, int n_in,
                              void* d_out, int out_size, void* d_ws, size_t ws_size,
                              hipStream_t stream) {
  const float* x1  = (const float*)d_in[0];   // Q
  const float* kw  = (const float*)d_in[1];   // K
  const float* val = (const float*)d_in[2];   // V
  float* out = (float*)d_out;
  attn_swp<<<dim3(NB*NH*(NS/QT)), dim3(256), 0, stream>>>(x1, kw, val, out);
}

// Round 12
// 90.826 us; speedup vs baseline: 1.5235x; 1.1502x over previous
//
#include <hip/hip_runtime.h>
#include <stdint.h>
#include <math.h>

#define NB 4
#define NH 16
#define NS 1024
#define ND 64
#define QT 128           // q rows per block (8 waves x 16 rows)
#define KT 64            // k cols per tile
#define NKT (NS/KT)      // 16
#define LDH 72           // f16 row pad: 144B rows, 16B-aligned units
#define SCALE_LOG2E 14426.950408889634f   // 10000 * log2(e); softmax done base-2
#define P_THRESH 5.9604645e-8f            // 2^-24: below this, dropout mask provably irrelevant

typedef _Float16 half8  __attribute__((ext_vector_type(8)));
typedef _Float16 half4  __attribute__((ext_vector_type(4)));
typedef _Float16 half2v __attribute__((ext_vector_type(2)));
typedef float    f32x4  __attribute__((ext_vector_type(4)));
typedef uint32_t uint4v __attribute__((ext_vector_type(4)));

// XOR-swizzled half-index for a [rows][LDH] f16 LDS array (T2; involution both sides).
__device__ __forceinline__ int swz(int row, int col){
  return row*LDH + ((((col>>3) ^ ((row>>2)&7)))<<3) + (col&7);
}

// ---------------- threefry2x32, key = (0, 42) ----------------
__device__ __forceinline__ void threefry2x32(uint32_t x0, uint32_t x1,
                                             uint32_t &o0, uint32_t &o1){
  const uint32_t ks0 = 0u, ks1 = 42u, ks2 = 0x1BD11BF0u; // 0x1BD11BDA ^ 0 ^ 42
  x0 += ks0; x1 += ks1;
#define TFR(r) { x0 += x1; x1 = __builtin_rotateleft32(x1,(r)); x1 ^= x0; }
  TFR(13) TFR(15) TFR(26) TFR(6)
  x0 += ks1; x1 += ks2 + 1u;
  TFR(17) TFR(29) TFR(16) TFR(24)
  x0 += ks2; x1 += ks0 + 2u;
  TFR(13) TFR(15) TFR(26) TFR(6)
  x0 += ks0; x1 += ks1 + 3u;
  TFR(17) TFR(29) TFR(16) TFR(24)
  x0 += ks1; x1 += ks2 + 4u;
  TFR(13) TFR(15) TFR(26) TFR(6)
  x0 += ks2; x1 += ks0 + 5u;
#undef TFR
  o0 = x0; o1 = x1;
}

// JAX partitionable threefry: bits(i) = o0^o1 of threefry(key, (0, i));
// keep iff (bits>>9) < 0x733333  (uniform < 0.9). Validated rounds 2..11.
__device__ __forceinline__ uint32_t keep_flat(uint32_t flat){
  uint32_t o0, o1;
  threefry2x32(0u, flat, o0, o1);
  return ((o0 ^ o1) >> 9) < 0x733333u ? 1u : 0u;
}

// MFMA flash attention, swapped-operand PV (P in registers, no P LDS array),
// QT=128 via 512-thread blocks: 2x K/V reuse, 2x occupancy (16 waves/CU).
// S^T = mfma(K, Q): C/D layout gives lane (lhi,llo) q-row q=llo (within the
// wave's 16-row group), k = nt*16 + 4*lhi + reg. Softmax per-lane + 2 shfl_xor.
// PV: O^T = mfma(V, P^T); P^T B-frags built in-register via shfl+cndmask —
// permutation-safe (A and B constructed with the same assumed k-map).
__global__ __launch_bounds__(512, 4) void attn_swp(
    const float* __restrict__ Qg, const float* __restrict__ Kg,
    const float* __restrict__ Vg, float* __restrict__ Og)
{
  __shared__ _Float16 Khi[KT*LDH];        // K hi parts, [kc][d] swizzled
  __shared__ _Float16 Klo[KT*LDH];        // K lo parts
  __shared__ _Float16 Vt [ND*LDH];        // V transposed [d][kc] swizzled

  const int tid  = threadIdx.x;
  const int wid  = tid >> 6;      // 0..7
  const int lane = tid & 63;
  const int lhi  = lane >> 4;     // 0..3
  const int llo  = lane & 15;

  // bijective XCD swizzle: 512 blocks, 8 XCDs, 64 contiguous work items each
  const int swzb = (blockIdx.x & 7) * 64 + (blockIdx.x >> 3);
  const int bh  = swzb >> 3;      // 0..63
  const int qt  = swzb & 7;       // 0..7 (128-row q tiles)

  // shuffle source lanes for P^T B-frag build (w<2 -> sl0, w>=2 -> sl1)
  const int sl0 = ((lane & 16) << 1) + llo;   // (lhi&1)*32 + llo
  const int sl1 = sl0 + 16;

  // ---- Q B-fragments (registers for whole kernel), hi/lo fp16 split
  half8 qhi[2], qlo[2];
  {
    const float* qsrc = Qg + ((size_t)bh*NS + qt*QT + wid*16 + llo)*ND;
    #pragma unroll
    for (int ks = 0; ks < 2; ++ks) {
      const float* p = qsrc + ks*32 + lhi*8;
      float4 a = *(const float4*)p;
      float4 b = *(const float4*)(p + 4);
      float v[8] = {a.x,a.y,a.z,a.w,b.x,b.y,b.z,b.w};
      #pragma unroll
      for (int j = 0; j < 8; ++j) {
        _Float16 h = (_Float16)v[j];
        qhi[ks][j] = h;
        qlo[ks][j] = (_Float16)(v[j] - (float)h);
      }
    }
  }

  const float* srcK = Kg + (size_t)bh*NS*ND;
  const float* srcV = Vg + (size_t)bh*NS*ND;
  const int frow = tid >> 4;          // 0..31 (global-load row within 512-thread sweep)
  const int fcol = (tid & 15) * 4;    // d offset

  float4 pk[2], pv[2];
  #pragma unroll
  for (int r = 0; r < 2; ++r) {       // prefetch tile 0
    const size_t off = (size_t)(frow + 32*r)*ND + fcol;
    pk[r] = *(const float4*)(srcK + off);
    pv[r] = *(const float4*)(srcV + off);
  }

  f32x4 Oacc[4];                      // O^T: lane holds [d=nt*16+4lhi+reg][q=llo]
  #pragma unroll
  for (int nt=0;nt<4;++nt){ Oacc[nt][0]=0.f;Oacc[nt][1]=0.f;Oacc[nt][2]=0.f;Oacc[nt][3]=0.f; }
  float m_run = -INFINITY;            // scalar per lane (q-row), scaled-log2 units
  float l_run = 0.f;
  const uint32_t qrow_flat = (uint32_t)(bh*NS + qt*QT + wid*16 + llo);

  for (int kt = 0; kt < NKT; ++kt) {
    __syncthreads();   // A: all waves' prior-tile LDS reads complete
    // ---- LDS write phase (consumes pk/pv; compiler inserts vmcnt wait)
    #pragma unroll
    for (int r = 0; r < 2; ++r) {
      const int row = frow + 32*r;    // kc 0..63
      float vals[4] = {pk[r].x, pk[r].y, pk[r].z, pk[r].w};
      half4 h4, l4;
      #pragma unroll
      for (int j = 0; j < 4; ++j) {
        _Float16 h = (_Float16)vals[j];
        h4[j] = h;
        l4[j] = (_Float16)(vals[j] - (float)h);
      }
      const int ki = swz(row, fcol);  // fcol&7 ∈ {0,4}: 8B stays in one 16B unit
      *(half4*)&Khi[ki] = h4;
      *(half4*)&Klo[ki] = l4;
      float vv[4] = {pv[r].x, pv[r].y, pv[r].z, pv[r].w};
      #pragma unroll
      for (int j = 0; j < 4; ++j)
        Vt[swz(fcol+j, row)] = (_Float16)vv[j];   // transposed scalar, swizzled
    }
    __syncthreads();   // B: tiles ready
    // ---- issue next tile's global loads (latency hidden under compute)
    if (kt + 1 < NKT) {
      #pragma unroll
      for (int r = 0; r < 2; ++r) {
        const size_t off = (size_t)((kt+1)*KT + frow + 32*r)*ND + fcol;
        pk[r] = *(const float4*)(srcK + off);
        pv[r] = *(const float4*)(srcV + off);
      }
    }

    // ---- swapped QK^T: S^T[k][q] via 3-product fp16 split; acc fp32
    f32x4 St[4];
    #pragma unroll
    for (int nt=0;nt<4;++nt){ St[nt][0]=0.f;St[nt][1]=0.f;St[nt][2]=0.f;St[nt][3]=0.f; }
    #pragma unroll
    for (int ks = 0; ks < 2; ++ks) {
      #pragma unroll
      for (int nt = 0; nt < 4; ++nt) {
        const int ki = swz(nt*16 + llo, ks*32 + lhi*8);
        half8 kh = *(const half8*)&Khi[ki];
        half8 kl = *(const half8*)&Klo[ki];
        St[nt] = __builtin_amdgcn_mfma_f32_16x16x32_f16(kh, qhi[ks], St[nt], 0, 0, 0);
        St[nt] = __builtin_amdgcn_mfma_f32_16x16x32_f16(kh, qlo[ks], St[nt], 0, 0, 0);
        St[nt] = __builtin_amdgcn_mfma_f32_16x16x32_f16(kl, qhi[ks], St[nt], 0, 0, 0);
      }
    }

    // ---- per-lane online softmax in base-2 (lane owns one q-row, 16 k-values)
    #pragma unroll
    for (int nt = 0; nt < 4; ++nt)
      #pragma unroll
      for (int r = 0; r < 4; ++r) St[nt][r] *= SCALE_LOG2E;
    float tm = -INFINITY;
    #pragma unroll
    for (int nt = 0; nt < 4; ++nt) {
      float a = fmaxf(fmaxf(St[nt][0], St[nt][1]), fmaxf(St[nt][2], St[nt][3]));
      tm = fmaxf(tm, a);
    }
    tm = fmaxf(tm, __shfl_xor(tm, 16));
    tm = fmaxf(tm, __shfl_xor(tm, 32));
    const float mnew = fmaxf(m_run, tm);
    const float al   = exp2f(m_run - mnew);
    m_run = mnew;
    float ps = 0.f;
    #pragma unroll
    for (int nt = 0; nt < 4; ++nt) {
      #pragma unroll
      for (int r = 0; r < 4; ++r) {
        float p = exp2f(St[nt][r] - mnew);
        St[nt][r] = p;
        ps += p;
      }
    }
    ps += __shfl_xor(ps, 16);
    ps += __shfl_xor(ps, 32);
    l_run = l_run*al + ps;
    #pragma unroll
    for (int nt = 0; nt < 4; ++nt) {
      Oacc[nt][0]*=al; Oacc[nt][1]*=al; Oacc[nt][2]*=al; Oacc[nt][3]*=al;
    }

    // ---- need mask (element i = nt*4+reg -> k = nt*16 + 4*lhi + reg)
    uint32_t nm = 0u;
    #pragma unroll
    for (int i = 0; i < 16; ++i)
      if (St[i>>2][i&3] > P_THRESH) nm |= 1u << i;

    // ---- cvt P to packed fp16 (8 u32); ends St's f32 live range
    uint32_t p16[8];
    #pragma unroll
    for (int w = 0; w < 8; ++w) {
      half2v h;
      h[0] = (_Float16)St[w>>1][(2*w)&3];
      h[1] = (_Float16)St[w>>1][(2*w+1)&3];
      p16[w] = __builtin_bit_cast(uint32_t, h);
    }

    // ---- lazy exact-RNG: branches only update the 16-bit keep mask
    uint32_t km = 0xFFFFu;
    const uint32_t fb = qrow_flat*NS + (uint32_t)(kt*KT + 4*lhi);
    #pragma unroll
    for (int i = 0; i < 16; ++i) {
      if (__any((int)(nm & (1u << i)))) {
        if (!keep_flat(fb + (uint32_t)((i>>2)*16 + (i&3))))
          km &= ~(1u << i);
      }
    }
    #pragma unroll
    for (int w = 0; w < 8; ++w) {
      uint32_t msk = (((km >> (2*w)) & 1u) ? 0x0000FFFFu : 0u)
                   | (((km >> (2*w+1)) & 1u) ? 0xFFFF0000u : 0u);
      p16[w] &= msk;
    }

    // ---- PV: O^T += V * P^T  (A = V frags from Vt, B = P^T built via shfl)
    #pragma unroll
    for (int ks = 0; ks < 2; ++ks) {
      uint4v bw;
      #pragma unroll
      for (int w = 0; w < 4; ++w) {
        const int src = (w < 2) ? sl0 : sl1;
        uint32_t a = (uint32_t)__shfl((int)p16[4*ks + (w&1)],     src);
        uint32_t b = (uint32_t)__shfl((int)p16[4*ks + 2 + (w&1)], src);
        bw[w] = (lane & 32) ? b : a;
      }
      half8 pb = __builtin_bit_cast(half8, bw);
      #pragma unroll
      for (int nt = 0; nt < 4; ++nt) {
        half8 vb = *(const half8*)&Vt[swz(nt*16 + llo, ks*32 + lhi*8)];
        Oacc[nt] = __builtin_amdgcn_mfma_f32_16x16x32_f16(vb, pb, Oacc[nt], 0, 0, 0);
      }
    }
  }

  // ---- epilogue: O^T lane rows are contiguous d -> float4 stores
  const float sc = (1.0f/0.9f) / l_run;
  const size_t rowbase = ((size_t)bh*NS + qt*QT + wid*16 + llo)*ND;
  #pragma unroll
  for (int nt = 0; nt < 4; ++nt) {
    float4 o;
    o.x = Oacc[nt][0]*sc; o.y = Oacc[nt][1]*sc;
    o.z = Oacc[nt][2]*sc; o.w = Oacc[nt][3]*sc;
    *(float4*)(Og + rowbase + nt*16 + 4*lhi) = o;
  }
}

extern "C" void kernel_launch(void* const* d_in, const int* in_sizes, int n_in,
                              void* d_out, int out_size, void* d_ws, size_t ws_size,
                              hipStream_t stream) {
  const float* x1  = (const float*)d_in[0];   // Q
  const float* kw  = (const float*)d_in[1];   // K
  const float* val = (const float*)d_in[2];   // V
  float* out = (float*)d_out;
  attn_swp<<<dim3(NB*NH*(NS/QT)), dim3(512), 0, stream>>>(x1, kw, val, out);
}

// Round 13
// 79.170 us; speedup vs baseline: 1.7478x; 1.1472x over previous
//
#include <hip/hip_runtime.h>
#include <stdint.h>
#include <math.h>

#define NB 4
#define NH 16
#define NS 1024
#define ND 64
#define QT 128           // q rows per block (8 waves x 16 rows)
#define KT 64            // k cols per tile
#define NKT (NS/KT)      // 16
#define LDH 72           // f16 row pad: 144B rows, 16B-aligned units
#define SCALE_LOG2E 14426.950408889634f   // 10000 * log2(e); softmax done base-2
#define P_THRESH 5.9604645e-8f            // 2^-24: below this, dropout mask provably irrelevant
#define RNG_CAP 128      // per-wave compaction capacity (expected ~12 used)

typedef _Float16 half8  __attribute__((ext_vector_type(8)));
typedef _Float16 half4  __attribute__((ext_vector_type(4)));
typedef _Float16 half2v __attribute__((ext_vector_type(2)));
typedef float    f32x4  __attribute__((ext_vector_type(4)));
typedef uint32_t uint4v __attribute__((ext_vector_type(4)));

// XOR-swizzled half-index for a [rows][LDH] f16 LDS array (T2; involution both sides).
__device__ __forceinline__ int swz(int row, int col){
  return row*LDH + ((((col>>3) ^ ((row>>2)&7)))<<3) + (col&7);
}

// ---------------- threefry2x32, key = (0, 42) ----------------
__device__ __forceinline__ void threefry2x32(uint32_t x0, uint32_t x1,
                                             uint32_t &o0, uint32_t &o1){
  const uint32_t ks0 = 0u, ks1 = 42u, ks2 = 0x1BD11BF0u; // 0x1BD11BDA ^ 0 ^ 42
  x0 += ks0; x1 += ks1;
#define TFR(r) { x0 += x1; x1 = __builtin_rotateleft32(x1,(r)); x1 ^= x0; }
  TFR(13) TFR(15) TFR(26) TFR(6)
  x0 += ks1; x1 += ks2 + 1u;
  TFR(17) TFR(29) TFR(16) TFR(24)
  x0 += ks2; x1 += ks0 + 2u;
  TFR(13) TFR(15) TFR(26) TFR(6)
  x0 += ks0; x1 += ks1 + 3u;
  TFR(17) TFR(29) TFR(16) TFR(24)
  x0 += ks1; x1 += ks2 + 4u;
  TFR(13) TFR(15) TFR(26) TFR(6)
  x0 += ks2; x1 += ks0 + 5u;
#undef TFR
  o0 = x0; o1 = x1;
}

// JAX partitionable threefry: bits(i) = o0^o1 of threefry(key, (0, i));
// keep iff (bits>>9) < 0x733333  (uniform < 0.9). Validated rounds 2..12.
__device__ __forceinline__ uint32_t keep_flat(uint32_t flat){
  uint32_t o0, o1;
  threefry2x32(0u, flat, o0, o1);
  return ((o0 ^ o1) >> 9) < 0x733333u ? 1u : 0u;
}

// MFMA flash attention, swapped-operand PV, QT=128 (8 waves), WAVE-COMPACTED
// lazy dropout: per tile, needed RNG elements (~12/wave) are gathered into
// per-wave LDS scratch (one atomicAdd claim per lane) and evaluated in ONE
// batched 64-lane threefry pass, replacing per-slot __any firing (~2.7x64
// evaluations). RNG decisions bit-identical; only km bits cross branches.
__global__ __launch_bounds__(512, 4) void attn_swp(
    const float* __restrict__ Qg, const float* __restrict__ Kg,
    const float* __restrict__ Vg, float* __restrict__ Og)
{
  __shared__ _Float16 Khi[KT*LDH];        // K hi parts, [kc][d] swizzled
  __shared__ _Float16 Klo[KT*LDH];        // K lo parts
  __shared__ _Float16 Vt [ND*LDH];        // V transposed [d][kc] swizzled
  __shared__ uint32_t wflat[8][RNG_CAP];  // per-wave needed flat indices
  __shared__ uint32_t wkeep[8][RNG_CAP];  // per-wave keep results
  __shared__ uint32_t wcnt[8];            // per-wave claim counter

  const int tid  = threadIdx.x;
  const int wid  = tid >> 6;      // 0..7
  const int lane = tid & 63;
  const int lhi  = lane >> 4;     // 0..3
  const int llo  = lane & 15;

  // bijective XCD swizzle: 512 blocks, 8 XCDs, 64 contiguous work items each
  const int swzb = (blockIdx.x & 7) * 64 + (blockIdx.x >> 3);
  const int bh  = swzb >> 3;      // 0..63
  const int qt  = swzb & 7;       // 0..7 (128-row q tiles)

  // shuffle source lanes for P^T B-frag build (w<2 -> sl0, w>=2 -> sl1)
  const int sl0 = ((lane & 16) << 1) + llo;   // (lhi&1)*32 + llo
  const int sl1 = sl0 + 16;

  // ---- Q B-fragments (registers for whole kernel), hi/lo fp16 split
  half8 qhi[2], qlo[2];
  {
    const float* qsrc = Qg + ((size_t)bh*NS + qt*QT + wid*16 + llo)*ND;
    #pragma unroll
    for (int ks = 0; ks < 2; ++ks) {
      const float* p = qsrc + ks*32 + lhi*8;
      float4 a = *(const float4*)p;
      float4 b = *(const float4*)(p + 4);
      float v[8] = {a.x,a.y,a.z,a.w,b.x,b.y,b.z,b.w};
      #pragma unroll
      for (int j = 0; j < 8; ++j) {
        _Float16 h = (_Float16)v[j];
        qhi[ks][j] = h;
        qlo[ks][j] = (_Float16)(v[j] - (float)h);
      }
    }
  }

  const float* srcK = Kg + (size_t)bh*NS*ND;
  const float* srcV = Vg + (size_t)bh*NS*ND;
  const int frow = tid >> 4;          // 0..31 (global-load row within 512-thread sweep)
  const int fcol = (tid & 15) * 4;    // d offset

  float4 pk[2], pv[2];
  #pragma unroll
  for (int r = 0; r < 2; ++r) {       // prefetch tile 0
    const size_t off = (size_t)(frow + 32*r)*ND + fcol;
    pk[r] = *(const float4*)(srcK + off);
    pv[r] = *(const float4*)(srcV + off);
  }

  f32x4 Oacc[4];                      // O^T: lane holds [d=nt*16+4lhi+reg][q=llo]
  #pragma unroll
  for (int nt=0;nt<4;++nt){ Oacc[nt][0]=0.f;Oacc[nt][1]=0.f;Oacc[nt][2]=0.f;Oacc[nt][3]=0.f; }
  float m_run = -INFINITY;            // scalar per lane (q-row), scaled-log2 units
  float l_run = 0.f;
  const uint32_t qrow_flat = (uint32_t)(bh*NS + qt*QT + wid*16 + llo);

  for (int kt = 0; kt < NKT; ++kt) {
    __syncthreads();   // A: all waves' prior-tile LDS reads complete
    // ---- LDS write phase (consumes pk/pv; compiler inserts vmcnt wait)
    #pragma unroll
    for (int r = 0; r < 2; ++r) {
      const int row = frow + 32*r;    // kc 0..63
      float vals[4] = {pk[r].x, pk[r].y, pk[r].z, pk[r].w};
      half4 h4, l4;
      #pragma unroll
      for (int j = 0; j < 4; ++j) {
        _Float16 h = (_Float16)vals[j];
        h4[j] = h;
        l4[j] = (_Float16)(vals[j] - (float)h);
      }
      const int ki = swz(row, fcol);  // fcol&7 ∈ {0,4}: 8B stays in one 16B unit
      *(half4*)&Khi[ki] = h4;
      *(half4*)&Klo[ki] = l4;
      float vv[4] = {pv[r].x, pv[r].y, pv[r].z, pv[r].w};
      #pragma unroll
      for (int j = 0; j < 4; ++j)
        Vt[swz(fcol+j, row)] = (_Float16)vv[j];   // transposed scalar, swizzled
    }
    __syncthreads();   // B: tiles ready
    // ---- issue next tile's global loads (latency hidden under compute)
    if (kt + 1 < NKT) {
      #pragma unroll
      for (int r = 0; r < 2; ++r) {
        const size_t off = (size_t)((kt+1)*KT + frow + 32*r)*ND + fcol;
        pk[r] = *(const float4*)(srcK + off);
        pv[r] = *(const float4*)(srcV + off);
      }
    }

    // ---- swapped QK^T: S^T[k][q] via 3-product fp16 split; acc fp32
    f32x4 St[4];
    #pragma unroll
    for (int nt=0;nt<4;++nt){ St[nt][0]=0.f;St[nt][1]=0.f;St[nt][2]=0.f;St[nt][3]=0.f; }
    #pragma unroll
    for (int ks = 0; ks < 2; ++ks) {
      #pragma unroll
      for (int nt = 0; nt < 4; ++nt) {
        const int ki = swz(nt*16 + llo, ks*32 + lhi*8);
        half8 kh = *(const half8*)&Khi[ki];
        half8 kl = *(const half8*)&Klo[ki];
        St[nt] = __builtin_amdgcn_mfma_f32_16x16x32_f16(kh, qhi[ks], St[nt], 0, 0, 0);
        St[nt] = __builtin_amdgcn_mfma_f32_16x16x32_f16(kh, qlo[ks], St[nt], 0, 0, 0);
        St[nt] = __builtin_amdgcn_mfma_f32_16x16x32_f16(kl, qhi[ks], St[nt], 0, 0, 0);
      }
    }

    // ---- per-lane online softmax in base-2 (lane owns one q-row, 16 k-values)
    #pragma unroll
    for (int nt = 0; nt < 4; ++nt)
      #pragma unroll
      for (int r = 0; r < 4; ++r) St[nt][r] *= SCALE_LOG2E;
    float tm = -INFINITY;
    #pragma unroll
    for (int nt = 0; nt < 4; ++nt) {
      float a = fmaxf(fmaxf(St[nt][0], St[nt][1]), fmaxf(St[nt][2], St[nt][3]));
      tm = fmaxf(tm, a);
    }
    tm = fmaxf(tm, __shfl_xor(tm, 16));
    tm = fmaxf(tm, __shfl_xor(tm, 32));
    const float mnew = fmaxf(m_run, tm);
    const float al   = exp2f(m_run - mnew);
    m_run = mnew;
    float ps = 0.f;
    #pragma unroll
    for (int nt = 0; nt < 4; ++nt) {
      #pragma unroll
      for (int r = 0; r < 4; ++r) {
        float p = exp2f(St[nt][r] - mnew);
        St[nt][r] = p;
        ps += p;
      }
    }
    ps += __shfl_xor(ps, 16);
    ps += __shfl_xor(ps, 32);
    l_run = l_run*al + ps;
    #pragma unroll
    for (int nt = 0; nt < 4; ++nt) {
      Oacc[nt][0]*=al; Oacc[nt][1]*=al; Oacc[nt][2]*=al; Oacc[nt][3]*=al;
    }

    // ---- need mask (element i = nt*4+reg -> k = nt*16 + 4*lhi + reg)
    uint32_t nm = 0u;
    #pragma unroll
    for (int i = 0; i < 16; ++i)
      if (St[i>>2][i&3] > P_THRESH) nm |= 1u << i;

    // ---- cvt P to packed fp16 (8 u32); ends St's f32 live range
    uint32_t p16[8];
    #pragma unroll
    for (int w = 0; w < 8; ++w) {
      half2v h;
      h[0] = (_Float16)St[w>>1][(2*w)&3];
      h[1] = (_Float16)St[w>>1][(2*w+1)&3];
      p16[w] = __builtin_bit_cast(uint32_t, h);
    }

    // ---- wave-compacted exact RNG (~12 needed elems/wave/tile -> one pass)
    uint32_t km = 0xFFFFu;
    {
      if (lane == 0) wcnt[wid] = 0u;
      asm volatile("" ::: "memory");          // keep zeroing before the claim
      const uint32_t cnt = (uint32_t)__popc(nm);
      uint32_t off = 0u;
      if (cnt) off = atomicAdd(&wcnt[wid], cnt);
      const uint32_t fb = qrow_flat*NS + (uint32_t)(kt*KT + 4*lhi);
      const bool fits = (off + cnt) <= (uint32_t)RNG_CAP;
      // publish descriptors (fast path)
      if (fits) {
        uint32_t m = nm; uint32_t j = 0;
        while (m) {
          int i = __builtin_ffs((int)m) - 1; m &= m - 1u;
          wflat[wid][off + j] = fb + (uint32_t)(((i>>2)<<4) + (i&3));
          ++j;
        }
      }
      asm volatile("s_waitcnt lgkmcnt(0)" ::: "memory");  // writes visible wave-wide
      uint32_t total = wcnt[wid];
      if (total > (uint32_t)RNG_CAP) total = (uint32_t)RNG_CAP;
      // one batched pass (total ~12 expected)
      for (uint32_t base = 0; base < total; base += 64u) {
        const uint32_t idx = base + (uint32_t)lane;
        if (idx < total)
          wkeep[wid][idx] = keep_flat(wflat[wid][idx]);
      }
      asm volatile("s_waitcnt lgkmcnt(0)" ::: "memory");
      // readback (fast path) or direct evaluation (overflow fallback, ~never)
      if (fits) {
        uint32_t m = nm; uint32_t j = 0;
        while (m) {
          int i = __builtin_ffs((int)m) - 1; m &= m - 1u;
          if (!wkeep[wid][off + j]) km &= ~(1u << i);
          ++j;
        }
      } else {
        uint32_t m = nm;
        while (m) {
          int i = __builtin_ffs((int)m) - 1; m &= m - 1u;
          if (!keep_flat(fb + (uint32_t)(((i>>2)<<4) + (i&3)))) km &= ~(1u << i);
        }
      }
    }
    #pragma unroll
    for (int w = 0; w < 8; ++w) {
      uint32_t msk = (((km >> (2*w)) & 1u) ? 0x0000FFFFu : 0u)
                   | (((km >> (2*w+1)) & 1u) ? 0xFFFF0000u : 0u);
      p16[w] &= msk;
    }

    // ---- PV: O^T += V * P^T  (A = V frags from Vt, B = P^T built via shfl)
    #pragma unroll
    for (int ks = 0; ks < 2; ++ks) {
      uint4v bw;
      #pragma unroll
      for (int w = 0; w < 4; ++w) {
        const int src = (w < 2) ? sl0 : sl1;
        uint32_t a = (uint32_t)__shfl((int)p16[4*ks + (w&1)],     src);
        uint32_t b = (uint32_t)__shfl((int)p16[4*ks + 2 + (w&1)], src);
        bw[w] = (lane & 32) ? b : a;
      }
      half8 pb = __builtin_bit_cast(half8, bw);
      #pragma unroll
      for (int nt = 0; nt < 4; ++nt) {
        half8 vb = *(const half8*)&Vt[swz(nt*16 + llo, ks*32 + lhi*8)];
        Oacc[nt] = __builtin_amdgcn_mfma_f32_16x16x32_f16(vb, pb, Oacc[nt], 0, 0, 0);
      }
    }
  }

  // ---- epilogue: O^T lane rows are contiguous d -> float4 stores
  const float sc = (1.0f/0.9f) / l_run;
  const size_t rowbase = ((size_t)bh*NS + qt*QT + wid*16 + llo)*ND;
  #pragma unroll
  for (int nt = 0; nt < 4; ++nt) {
    float4 o;
    o.x = Oacc[nt][0]*sc; o.y = Oacc[nt][1]*sc;
    o.z = Oacc[nt][2]*sc; o.w = Oacc[nt][3]*sc;
    *(float4*)(Og + rowbase + nt*16 + 4*lhi) = o;
  }
}

extern "C" void kernel_launch(void* const* d_in, const int* in_sizes, int n_in,
                              void* d_out, int out_size, void* d_ws, size_t ws_size,
                              hipStream_t stream) {
  const float* x1  = (const float*)d_in[0];   // Q
  const float* kw  = (const float*)d_in[1];   // K
  const float* val = (const float*)d_in[2];   // V
  float* out = (float*)d_out;
  attn_swp<<<dim3(NB*NH*(NS/QT)), dim3(512), 0, stream>>>(x1, kw, val, out);
}